// Round 1
// baseline (82.302 us; speedup 1.0000x reference)
//
#include <hip/hip_runtime.h>
#include <math.h>

// FaceKernelCorrelation: B=8, N=16384, K=64, 4 kernel points per k, sigma=0.2
// Pipeline:
//  1) kc_kernel: gather fea (center + 3 neighbor normals), compute
//     kc[b,k,n] = mean_{i,j} exp(-|fea_i - w_kj|^2 / (2 sigma^2)),
//     write kc to d_out, and deterministic per-block partial sums of
//     kc and kc^2 per k into d_ws (no atomics).
//  2) stats_kernel: reduce partials -> scale[k] = gamma/sqrt(var+eps),
//     shift[k] = beta - mean*scale.
//  3) bn_kernel: in-place float4 y = relu(kc*scale + shift).

#define NFACES 16384
#define BATCH  8
#define KK     64
#define NBLK1  512            // (BATCH*NFACES)/256

// C = -1/(2*sigma^2) * log2(e)  with sigma = 0.2
__device__ __constant__ const float C_SCALE = -18.033688011112043f;

__global__ __launch_bounds__(256) void kc_kernel(
    const float* __restrict__ normals,   // [B,3,N]
    const int*   __restrict__ nbr,       // [B,N,3]
    const float* __restrict__ walpha,    // [K*4]
    const float* __restrict__ wbeta,     // [K*4]
    float*       __restrict__ out,       // [B,K,N] (kc values)
    float*       __restrict__ psum,      // [K, NBLK1]
    float*       __restrict__ psumsq)    // [K, NBLK1]
{
    __shared__ float4 sW[KK * 4];        // (m2*wx, m2*wy, m2*wz, C*|w|^2)
    __shared__ float  sPart[KK][8];      // [k][wave*2 + {sum,sumsq}]

    const int tid = threadIdx.x;

    // Build kernel-point table: 256 threads -> 256 (k,j) entries
    {
        float a = walpha[tid];
        float b = wbeta[tid];
        float sa = sinf(a), ca = cosf(a);
        float sb = sinf(b), cb = cosf(b);
        float wx = sa * cb, wy = sa * sb, wz = ca;
        float wn2 = wx * wx + wy * wy + wz * wz;
        const float m2 = -2.0f * C_SCALE;
        sW[tid] = make_float4(m2 * wx, m2 * wy, m2 * wz, C_SCALE * wn2);
    }
    __syncthreads();

    const int b = blockIdx.x >> 6;                   // blockIdx / 64
    const int n = ((blockIdx.x & 63) << 8) + tid;    // face index
    const float* nb_ = normals + (size_t)b * 3 * NFACES;

    float fx[4], fy[4], fz[4], fa[4];
    fx[0] = nb_[n];
    fy[0] = nb_[NFACES + n];
    fz[0] = nb_[2 * NFACES + n];
    const int* ip = nbr + ((size_t)b * NFACES + n) * 3;
#pragma unroll
    for (int j = 0; j < 3; ++j) {
        int idx = ip[j];
        fx[j + 1] = nb_[idx];
        fy[j + 1] = nb_[NFACES + idx];
        fz[j + 1] = nb_[2 * NFACES + idx];
    }
#pragma unroll
    for (int i = 0; i < 4; ++i)
        fa[i] = C_SCALE * (fx[i] * fx[i] + fy[i] * fy[i] + fz[i] * fz[i]);

    const int lane = tid & 63;
    const int wid  = tid >> 6;
    float* outp = out + (size_t)b * KK * NFACES + n;

    for (int k = 0; k < KK; ++k) {
        float s = 0.0f;
#pragma unroll
        for (int j = 0; j < 4; ++j) {
            float4 w = sW[k * 4 + j];
#pragma unroll
            for (int i = 0; i < 4; ++i) {
                float t = __builtin_fmaf(w.z, fz[i], w.w);
                t = __builtin_fmaf(w.y, fy[i], t);
                t = __builtin_fmaf(w.x, fx[i], t);
                t += fa[i];
                s += __builtin_exp2f(t);
            }
        }
        float kc = s * 0.0625f;
        outp[(size_t)k * NFACES] = kc;

        // wave-level reduction of kc and kc^2
        float v = kc, v2 = kc * kc;
#pragma unroll
        for (int off = 32; off > 0; off >>= 1) {
            v  += __shfl_down(v,  off, 64);
            v2 += __shfl_down(v2, off, 64);
        }
        if (lane == 0) {
            sPart[k][wid * 2]     = v;
            sPart[k][wid * 2 + 1] = v2;
        }
    }
    __syncthreads();

    if (tid < KK) {
        float s0 = sPart[tid][0] + sPart[tid][2] + sPart[tid][4] + sPart[tid][6];
        float s1 = sPart[tid][1] + sPart[tid][3] + sPart[tid][5] + sPart[tid][7];
        psum[tid * NBLK1 + blockIdx.x]   = s0;
        psumsq[tid * NBLK1 + blockIdx.x] = s1;
    }
}

__global__ __launch_bounds__(256) void stats_kernel(
    const float* __restrict__ psum,
    const float* __restrict__ psumsq,
    const float* __restrict__ gamma,
    const float* __restrict__ beta,
    float*       __restrict__ scale,
    float*       __restrict__ shift)
{
    const int k = blockIdx.x;
    const int tid = threadIdx.x;
    float s = psum[k * NBLK1 + tid]   + psum[k * NBLK1 + 256 + tid];
    float q = psumsq[k * NBLK1 + tid] + psumsq[k * NBLK1 + 256 + tid];
    __shared__ float sS[4], sQ[4];
#pragma unroll
    for (int off = 32; off > 0; off >>= 1) {
        s += __shfl_down(s, off, 64);
        q += __shfl_down(q, off, 64);
    }
    const int lane = tid & 63, wid = tid >> 6;
    if (lane == 0) { sS[wid] = s; sQ[wid] = q; }
    __syncthreads();
    if (tid == 0) {
        float sum = sS[0] + sS[1] + sS[2] + sS[3];
        float sq  = sQ[0] + sQ[1] + sQ[2] + sQ[3];
        const float invN = 1.0f / (float)(BATCH * NFACES);
        float mean = sum * invN;
        float var  = sq * invN - mean * mean;
        float sc = gamma[k] / sqrtf(var + 1e-5f);
        scale[k] = sc;
        shift[k] = beta[k] - mean * sc;
    }
}

__global__ __launch_bounds__(256) void bn_kernel(
    float* __restrict__ out,
    const float* __restrict__ scale,
    const float* __restrict__ shift)
{
    const size_t idx = (size_t)blockIdx.x * 256 + threadIdx.x;  // float4 index
    const int k = (int)((idx >> 12) & 63);   // float idx = idx*4; k = (f>>14)&63
    float4 v = reinterpret_cast<float4*>(out)[idx];
    const float sc = scale[k], sh = shift[k];
    v.x = fmaxf(__builtin_fmaf(v.x, sc, sh), 0.0f);
    v.y = fmaxf(__builtin_fmaf(v.y, sc, sh), 0.0f);
    v.z = fmaxf(__builtin_fmaf(v.z, sc, sh), 0.0f);
    v.w = fmaxf(__builtin_fmaf(v.w, sc, sh), 0.0f);
    reinterpret_cast<float4*>(out)[idx] = v;
}

extern "C" void kernel_launch(void* const* d_in, const int* in_sizes, int n_in,
                              void* d_out, int out_size, void* d_ws, size_t ws_size,
                              hipStream_t stream) {
    const float* normals = (const float*)d_in[0];
    const int*   nbr     = (const int*)d_in[1];
    const float* walpha  = (const float*)d_in[2];
    const float* wbeta   = (const float*)d_in[3];
    const float* gamma   = (const float*)d_in[4];
    const float* beta    = (const float*)d_in[5];
    float* out = (float*)d_out;

    float* psum   = (float*)d_ws;              // [64][512]
    float* psumsq = psum + KK * NBLK1;         // [64][512]
    float* scale  = psumsq + KK * NBLK1;       // [64]
    float* shift  = scale + KK;                // [64]

    kc_kernel<<<NBLK1, 256, 0, stream>>>(normals, nbr, walpha, wbeta, out, psum, psumsq);
    stats_kernel<<<KK, 256, 0, stream>>>(psum, psumsq, gamma, beta, scale, shift);

    const int total_f4 = (BATCH * KK * NFACES) / 4;   // 2,097,152
    bn_kernel<<<total_f4 / 256, 256, 0, stream>>>(out, scale, shift);
}

// Round 2
// 74.431 us; speedup vs baseline: 1.1057x; 1.1057x over previous
//
#include <hip/hip_runtime.h>
#include <math.h>

// FaceKernelCorrelation: B=8, N=16384, K=64, 4 kernel points per k, sigma=0.2
// Pipeline (reduction stripped out of the compute kernel — the per-k shuffle
// reduce was a 768-deep dependent ds_bpermute chain and dominated R0's 70us):
//  1) kc_kernel:  gather fea, compute kc[b,k,n], store to d_out. No reduction.
//  2) sum_kernel: grid (k,b) = 512 blocks, coalesced float4 re-read of kc
//     (L3-resident, 33.5MB), per-(k,b) partial sum / sumsq -> d_ws.
//  3) fin_kernel: 1 block, 64 threads: fold partials -> scale/shift.
//  4) bn_kernel:  in-place float4 y = relu(kc*scale + shift).

#define NFACES 16384
#define BATCH  8
#define KK     64
#define NBLK1  512            // (BATCH*NFACES)/256

// C = -1/(2*sigma^2) * log2(e)  with sigma = 0.2
__device__ __constant__ const float C_SCALE = -18.033688011112043f;

__global__ __launch_bounds__(256) void kc_kernel(
    const float* __restrict__ normals,   // [B,3,N]
    const int*   __restrict__ nbr,       // [B,N,3]
    const float* __restrict__ walpha,    // [K*4]
    const float* __restrict__ wbeta,     // [K*4]
    float*       __restrict__ out)       // [B,K,N] (kc values)
{
    __shared__ float4 sW[KK * 4];        // (m2*wx, m2*wy, m2*wz, C*|w|^2)

    const int tid = threadIdx.x;

    // Build kernel-point table: 256 threads -> 256 (k,j) entries
    {
        float a = walpha[tid];
        float b = wbeta[tid];
        float sa = sinf(a), ca = cosf(a);
        float sb = sinf(b), cb = cosf(b);
        float wx = sa * cb, wy = sa * sb, wz = ca;
        float wn2 = wx * wx + wy * wy + wz * wz;
        const float m2 = -2.0f * C_SCALE;
        sW[tid] = make_float4(m2 * wx, m2 * wy, m2 * wz, C_SCALE * wn2);
    }
    __syncthreads();

    const int b = blockIdx.x >> 6;                   // blockIdx / 64
    const int n = ((blockIdx.x & 63) << 8) + tid;    // face index
    const float* nb_ = normals + (size_t)b * 3 * NFACES;

    float fx[4], fy[4], fz[4], fa[4];
    fx[0] = nb_[n];
    fy[0] = nb_[NFACES + n];
    fz[0] = nb_[2 * NFACES + n];
    const int* ip = nbr + ((size_t)b * NFACES + n) * 3;
#pragma unroll
    for (int j = 0; j < 3; ++j) {
        int idx = ip[j];
        fx[j + 1] = nb_[idx];
        fy[j + 1] = nb_[NFACES + idx];
        fz[j + 1] = nb_[2 * NFACES + idx];
    }
#pragma unroll
    for (int i = 0; i < 4; ++i)
        fa[i] = C_SCALE * (fx[i] * fx[i] + fy[i] * fy[i] + fz[i] * fz[i]);

    float* outp = out + (size_t)b * KK * NFACES + n;

#pragma unroll 4
    for (int k = 0; k < KK; ++k) {
        float s = 0.0f;
#pragma unroll
        for (int j = 0; j < 4; ++j) {
            float4 w = sW[k * 4 + j];
#pragma unroll
            for (int i = 0; i < 4; ++i) {
                float t = __builtin_fmaf(w.z, fz[i], w.w);
                t = __builtin_fmaf(w.y, fy[i], t);
                t = __builtin_fmaf(w.x, fx[i], t);
                t += fa[i];
                s += __builtin_exp2f(t);
            }
        }
        outp[(size_t)k * NFACES] = s * 0.0625f;
    }
}

// Per-(k,b) partial sums of kc and kc^2. Grid = 512 = b*64 + k, block = 256.
__global__ __launch_bounds__(256) void sum_kernel(
    const float* __restrict__ out,       // [B,K,N]
    float*       __restrict__ psum,      // [K*8]  (k*8 + b)
    float*       __restrict__ psumsq)    // [K*8]
{
    const int k = blockIdx.x & 63;
    const int b = blockIdx.x >> 6;
    const float4* p = reinterpret_cast<const float4*>(
        out + ((size_t)b * KK + k) * NFACES);

    float s = 0.0f, q = 0.0f;
#pragma unroll
    for (int i = 0; i < 16; ++i) {
        float4 v = p[i * 256 + threadIdx.x];
        s += (v.x + v.y) + (v.z + v.w);
        q += (v.x * v.x + v.y * v.y) + (v.z * v.z + v.w * v.w);
    }

    __shared__ float sS[4], sQ[4];
#pragma unroll
    for (int off = 32; off > 0; off >>= 1) {
        s += __shfl_down(s, off, 64);
        q += __shfl_down(q, off, 64);
    }
    const int lane = threadIdx.x & 63, wid = threadIdx.x >> 6;
    if (lane == 0) { sS[wid] = s; sQ[wid] = q; }
    __syncthreads();
    if (threadIdx.x == 0) {
        psum[k * 8 + b]   = (sS[0] + sS[1]) + (sS[2] + sS[3]);
        psumsq[k * 8 + b] = (sQ[0] + sQ[1]) + (sQ[2] + sQ[3]);
    }
}

__global__ __launch_bounds__(64) void fin_kernel(
    const float* __restrict__ psum,
    const float* __restrict__ psumsq,
    const float* __restrict__ gamma,
    const float* __restrict__ beta,
    float*       __restrict__ scale,
    float*       __restrict__ shift)
{
    const int k = threadIdx.x;
    float sum = 0.0f, sq = 0.0f;
#pragma unroll
    for (int b = 0; b < 8; ++b) {
        sum += psum[k * 8 + b];
        sq  += psumsq[k * 8 + b];
    }
    const float invN = 1.0f / (float)(BATCH * NFACES);
    float mean = sum * invN;
    float var  = sq * invN - mean * mean;
    float sc = gamma[k] / sqrtf(var + 1e-5f);
    scale[k] = sc;
    shift[k] = beta[k] - mean * sc;
}

__global__ __launch_bounds__(256) void bn_kernel(
    float* __restrict__ out,
    const float* __restrict__ scale,
    const float* __restrict__ shift)
{
    const size_t idx = (size_t)blockIdx.x * 256 + threadIdx.x;  // float4 index
    const int k = (int)((idx >> 12) & 63);   // float idx = idx*4; k = (f>>14)&63
    float4 v = reinterpret_cast<float4*>(out)[idx];
    const float sc = scale[k], sh = shift[k];
    v.x = fmaxf(__builtin_fmaf(v.x, sc, sh), 0.0f);
    v.y = fmaxf(__builtin_fmaf(v.y, sc, sh), 0.0f);
    v.z = fmaxf(__builtin_fmaf(v.z, sc, sh), 0.0f);
    v.w = fmaxf(__builtin_fmaf(v.w, sc, sh), 0.0f);
    reinterpret_cast<float4*>(out)[idx] = v;
}

extern "C" void kernel_launch(void* const* d_in, const int* in_sizes, int n_in,
                              void* d_out, int out_size, void* d_ws, size_t ws_size,
                              hipStream_t stream) {
    const float* normals = (const float*)d_in[0];
    const int*   nbr     = (const int*)d_in[1];
    const float* walpha  = (const float*)d_in[2];
    const float* wbeta   = (const float*)d_in[3];
    const float* gamma   = (const float*)d_in[4];
    const float* beta    = (const float*)d_in[5];
    float* out = (float*)d_out;

    float* psum   = (float*)d_ws;              // [64*8]
    float* psumsq = psum + KK * 8;             // [64*8]
    float* scale  = psumsq + KK * 8;           // [64]
    float* shift  = scale + KK;                // [64]

    kc_kernel<<<NBLK1, 256, 0, stream>>>(normals, nbr, walpha, wbeta, out);
    sum_kernel<<<NBLK1, 256, 0, stream>>>(out, psum, psumsq);
    fin_kernel<<<1, 64, 0, stream>>>(psum, psumsq, gamma, beta, scale, shift);

    const int total_f4 = (BATCH * KK * NFACES) / 4;   // 2,097,152
    bn_kernel<<<total_f4 / 256, 256, 0, stream>>>(out, scale, shift);
}

// Round 4
// 56.776 us; speedup vs baseline: 1.4496x; 1.3110x over previous
//
#include <hip/hip_runtime.h>
#include <math.h>

// FaceKernelCorrelation: B=8, N=16384, K=64, 4 kernel points per k, sigma=0.2
// R3 (resubmit — R3 bench died with UnresponsiveContainer, no data):
// kc_kernel restructured for occupancy — each block = 64 faces x 4 waves,
// each wave owns 16 k's (grid 2048, 8 waves/SIMD) and raw v_exp_f32 via
// __builtin_amdgcn_exp2f (arg <= 0 always; flush-to-zero underflow is fine).
//  1) kc_kernel:  gather fea, compute kc[b,k,n], store to d_out.
//  2) sum_kernel: grid (k,b) = 512 blocks, coalesced float4 re-read of kc
//     (L3-resident), per-(k,b) partial sum / sumsq -> d_ws.
//  3) fin_kernel: 1 block, 64 threads: fold partials -> scale/shift.
//  4) bn_kernel:  in-place float4 y = relu(kc*scale + shift).

#define NFACES 16384
#define BATCH  8
#define KK     64

// C = -1/(2*sigma^2) * log2(e)  with sigma = 0.2
__device__ __constant__ const float C_SCALE = -18.033688011112043f;

__global__ __launch_bounds__(256, 8) void kc_kernel(
    const float* __restrict__ normals,   // [B,3,N]
    const int*   __restrict__ nbr,       // [B,N,3]
    const float* __restrict__ walpha,    // [K*4]
    const float* __restrict__ wbeta,     // [K*4]
    float*       __restrict__ out)       // [B,K,N] (kc values)
{
    __shared__ float4 sW[KK * 4];        // (m2*wx, m2*wy, m2*wz, C*|w|^2)

    const int tid = threadIdx.x;

    // Build kernel-point table: 256 threads -> 256 (k,j) entries
    {
        float a = walpha[tid];
        float b = wbeta[tid];
        float sa = sinf(a), ca = cosf(a);
        float sb = sinf(b), cb = cosf(b);
        float wx = sa * cb, wy = sa * sb, wz = ca;
        float wn2 = wx * wx + wy * wy + wz * wz;
        const float m2 = -2.0f * C_SCALE;
        sW[tid] = make_float4(m2 * wx, m2 * wy, m2 * wz, C_SCALE * wn2);
    }
    __syncthreads();

    const int b  = blockIdx.x >> 8;                        // blockIdx / 256
    const int n  = ((blockIdx.x & 255) << 6) + (tid & 63); // face index
    const int kq = tid >> 6;                               // wave id: k-quarter

    const float* nb_ = normals + (size_t)b * 3 * NFACES;

    float fx[4], fy[4], fz[4], fa[4];
    fx[0] = nb_[n];
    fy[0] = nb_[NFACES + n];
    fz[0] = nb_[2 * NFACES + n];
    const int* ip = nbr + ((size_t)b * NFACES + n) * 3;
#pragma unroll
    for (int j = 0; j < 3; ++j) {
        int idx = ip[j];
        fx[j + 1] = nb_[idx];
        fy[j + 1] = nb_[NFACES + idx];
        fz[j + 1] = nb_[2 * NFACES + idx];
    }
#pragma unroll
    for (int i = 0; i < 4; ++i)
        fa[i] = C_SCALE * (fx[i] * fx[i] + fy[i] * fy[i] + fz[i] * fz[i]);

    float* outp = out + ((size_t)b * KK + kq * 16) * NFACES + n;
    const float4* wp = &sW[kq * 64];

#pragma unroll 2
    for (int kk = 0; kk < 16; ++kk) {
        float s = 0.0f;
#pragma unroll
        for (int j = 0; j < 4; ++j) {
            float4 w = wp[kk * 4 + j];
#pragma unroll
            for (int i = 0; i < 4; ++i) {
                float t = __builtin_fmaf(w.z, fz[i], w.w);
                t = __builtin_fmaf(w.y, fy[i], t);
                t = __builtin_fmaf(w.x, fx[i], t);
                t += fa[i];
                s += __builtin_amdgcn_exp2f(t);
            }
        }
        outp[(size_t)kk * NFACES] = s * 0.0625f;
    }
}

// Per-(k,b) partial sums of kc and kc^2. Grid = 512 = b*64 + k, block = 256.
__global__ __launch_bounds__(256) void sum_kernel(
    const float* __restrict__ out,       // [B,K,N]
    float*       __restrict__ psum,      // [K*8]  (k*8 + b)
    float*       __restrict__ psumsq)    // [K*8]
{
    const int k = blockIdx.x & 63;
    const int b = blockIdx.x >> 6;
    const float4* p = reinterpret_cast<const float4*>(
        out + ((size_t)b * KK + k) * NFACES);

    float s = 0.0f, q = 0.0f;
#pragma unroll
    for (int i = 0; i < 16; ++i) {
        float4 v = p[i * 256 + threadIdx.x];
        s += (v.x + v.y) + (v.z + v.w);
        q += (v.x * v.x + v.y * v.y) + (v.z * v.z + v.w * v.w);
    }

    __shared__ float sS[4], sQ[4];
#pragma unroll
    for (int off = 32; off > 0; off >>= 1) {
        s += __shfl_down(s, off, 64);
        q += __shfl_down(q, off, 64);
    }
    const int lane = threadIdx.x & 63, wid = threadIdx.x >> 6;
    if (lane == 0) { sS[wid] = s; sQ[wid] = q; }
    __syncthreads();
    if (threadIdx.x == 0) {
        psum[k * 8 + b]   = (sS[0] + sS[1]) + (sS[2] + sS[3]);
        psumsq[k * 8 + b] = (sQ[0] + sQ[1]) + (sQ[2] + sQ[3]);
    }
}

__global__ __launch_bounds__(64) void fin_kernel(
    const float* __restrict__ psum,
    const float* __restrict__ psumsq,
    const float* __restrict__ gamma,
    const float* __restrict__ beta,
    float*       __restrict__ scale,
    float*       __restrict__ shift)
{
    const int k = threadIdx.x;
    float sum = 0.0f, sq = 0.0f;
#pragma unroll
    for (int b = 0; b < 8; ++b) {
        sum += psum[k * 8 + b];
        sq  += psumsq[k * 8 + b];
    }
    const float invN = 1.0f / (float)(BATCH * NFACES);
    float mean = sum * invN;
    float var  = sq * invN - mean * mean;
    float sc = gamma[k] / sqrtf(var + 1e-5f);
    scale[k] = sc;
    shift[k] = beta[k] - mean * sc;
}

__global__ __launch_bounds__(256) void bn_kernel(
    float* __restrict__ out,
    const float* __restrict__ scale,
    const float* __restrict__ shift)
{
    const size_t idx = (size_t)blockIdx.x * 256 + threadIdx.x;  // float4 index
    const int k = (int)((idx >> 12) & 63);   // float idx = idx*4; k = (f>>14)&63
    float4 v = reinterpret_cast<float4*>(out)[idx];
    const float sc = scale[k], sh = shift[k];
    v.x = fmaxf(__builtin_fmaf(v.x, sc, sh), 0.0f);
    v.y = fmaxf(__builtin_fmaf(v.y, sc, sh), 0.0f);
    v.z = fmaxf(__builtin_fmaf(v.z, sc, sh), 0.0f);
    v.w = fmaxf(__builtin_fmaf(v.w, sc, sh), 0.0f);
    reinterpret_cast<float4*>(out)[idx] = v;
}

extern "C" void kernel_launch(void* const* d_in, const int* in_sizes, int n_in,
                              void* d_out, int out_size, void* d_ws, size_t ws_size,
                              hipStream_t stream) {
    const float* normals = (const float*)d_in[0];
    const int*   nbr     = (const int*)d_in[1];
    const float* walpha  = (const float*)d_in[2];
    const float* wbeta   = (const float*)d_in[3];
    const float* gamma   = (const float*)d_in[4];
    const float* beta    = (const float*)d_in[5];
    float* out = (float*)d_out;

    float* psum   = (float*)d_ws;              // [64*8]
    float* psumsq = psum + KK * 8;             // [64*8]
    float* scale  = psumsq + KK * 8;           // [64]
    float* shift  = scale + KK;                // [64]

    kc_kernel<<<BATCH * 256, 256, 0, stream>>>(normals, nbr, walpha, wbeta, out);
    sum_kernel<<<512, 256, 0, stream>>>(out, psum, psumsq);
    fin_kernel<<<1, 64, 0, stream>>>(psum, psumsq, gamma, beta, scale, shift);

    const int total_f4 = (BATCH * KK * NFACES) / 4;   // 2,097,152
    bn_kernel<<<total_f4 / 256, 256, 0, stream>>>(out, scale, shift);
}

// Round 7
// 54.067 us; speedup vs baseline: 1.5222x; 1.0501x over previous
//
#include <hip/hip_runtime.h>
#include <math.h>

// FaceKernelCorrelation: B=8, N=16384, K=64, 4 kernel points per k, sigma=0.2
// R7 (2nd resubmit of R5 — R5/R6 benches both died with UnresponsiveContainer):
// fuse the stats reduction back into kc via per-wave LDS transpose
// (conflict-free [4][64][17] tile, no extra barrier, ~300 cyc/wave) — removes
// the 33.5MB sum_kernel pass entirely. fin shrinks to 64 blocks.
//  1) kc_kernel:  gather fea, compute kc[b,k,n], store to d_out, and emit
//     per-(k,block) partial sum/sumsq via LDS-transpose wave reduce.
//  2) fin_kernel: 64 blocks (one per k): reduce 2048 partials -> scale/shift.
//  3) bn_kernel:  in-place float4 y = relu(kc*scale + shift).

#define NFACES 16384
#define BATCH  8
#define KK     64
#define NBLK   2048            // kc grid: BATCH * (NFACES/64)

// C = -1/(2*sigma^2) * log2(e)  with sigma = 0.2
__device__ __constant__ const float C_SCALE = -18.033688011112043f;

__global__ __launch_bounds__(256, 7) void kc_kernel(
    const float* __restrict__ normals,   // [B,3,N]
    const int*   __restrict__ nbr,       // [B,N,3]
    const float* __restrict__ walpha,    // [K*4]
    const float* __restrict__ wbeta,     // [K*4]
    float*       __restrict__ out,       // [B,K,N] (kc values)
    float*       __restrict__ psum,      // [K][NBLK]
    float*       __restrict__ psumsq)    // [K][NBLK]
{
    __shared__ float4 sW[KK * 4];        // (m2*wx, m2*wy, m2*wz, C*|w|^2)
    __shared__ float  sT[4][64][17];     // [wave][lane][k] transpose tile

    const int tid = threadIdx.x;

    // Build kernel-point table: 256 threads -> 256 (k,j) entries
    {
        float a = walpha[tid];
        float b = wbeta[tid];
        float sa = sinf(a), ca = cosf(a);
        float sb = sinf(b), cb = cosf(b);
        float wx = sa * cb, wy = sa * sb, wz = ca;
        float wn2 = wx * wx + wy * wy + wz * wz;
        const float m2 = -2.0f * C_SCALE;
        sW[tid] = make_float4(m2 * wx, m2 * wy, m2 * wz, C_SCALE * wn2);
    }
    __syncthreads();

    const int b    = blockIdx.x >> 8;                       // blockIdx / 256
    const int lane = tid & 63;
    const int n    = ((blockIdx.x & 255) << 6) + lane;      // face index
    const int kq   = tid >> 6;                              // wave id: k-quarter

    const float* nb_ = normals + (size_t)b * 3 * NFACES;

    float fx[4], fy[4], fz[4], fa[4];
    fx[0] = nb_[n];
    fy[0] = nb_[NFACES + n];
    fz[0] = nb_[2 * NFACES + n];
    const int* ip = nbr + ((size_t)b * NFACES + n) * 3;
#pragma unroll
    for (int j = 0; j < 3; ++j) {
        int idx = ip[j];
        fx[j + 1] = nb_[idx];
        fy[j + 1] = nb_[NFACES + idx];
        fz[j + 1] = nb_[2 * NFACES + idx];
    }
#pragma unroll
    for (int i = 0; i < 4; ++i)
        fa[i] = C_SCALE * (fx[i] * fx[i] + fy[i] * fy[i] + fz[i] * fz[i]);

    float* outp = out + ((size_t)b * KK + kq * 16) * NFACES + n;
    const float4* wp = &sW[kq * 64];

#pragma unroll 4
    for (int kk = 0; kk < 16; ++kk) {
        float s = 0.0f;
#pragma unroll
        for (int j = 0; j < 4; ++j) {
            float4 w = wp[kk * 4 + j];
#pragma unroll
            for (int i = 0; i < 4; ++i) {
                float t = __builtin_fmaf(w.z, fz[i], w.w);
                t = __builtin_fmaf(w.y, fy[i], t);
                t = __builtin_fmaf(w.x, fx[i], t);
                t += fa[i];
                s += __builtin_amdgcn_exp2f(t);
            }
        }
        float kc = s * 0.0625f;
        outp[(size_t)kk * NFACES] = kc;
        sT[kq][lane][kk] = kc;               // intra-wave: no barrier needed
    }

    // Per-wave transpose reduce over this wave's 64 faces, 16 k's.
    // Reads: bank = (16*seg + 17*j + kk) % 32 -> exactly 2-way, free.
    {
        const int kk = lane & 15, seg = lane >> 4;
        float v = 0.0f, q = 0.0f;
#pragma unroll
        for (int j = 0; j < 16; ++j) {
            float x = sT[kq][seg * 16 + j][kk];
            v += x;
            q = __builtin_fmaf(x, x, q);
        }
        v += __shfl_xor(v, 16, 64);  q += __shfl_xor(q, 16, 64);
        v += __shfl_xor(v, 32, 64);  q += __shfl_xor(q, 32, 64);
        if (seg == 0) {
            const int k = kq * 16 + kk;
            psum[(size_t)k * NBLK + blockIdx.x]   = v;
            psumsq[(size_t)k * NBLK + blockIdx.x] = q;
        }
    }
}

// One block per k: reduce 2048 partials -> scale/shift.
__global__ __launch_bounds__(256) void fin_kernel(
    const float* __restrict__ psum,
    const float* __restrict__ psumsq,
    const float* __restrict__ gamma,
    const float* __restrict__ beta,
    float*       __restrict__ scale,
    float*       __restrict__ shift)
{
    const int k = blockIdx.x;
    const int tid = threadIdx.x;
    const float4* ps = reinterpret_cast<const float4*>(psum   + (size_t)k * NBLK);
    const float4* pq = reinterpret_cast<const float4*>(psumsq + (size_t)k * NBLK);

    float s = 0.0f, q = 0.0f;
#pragma unroll
    for (int i = 0; i < 2; ++i) {
        float4 a = ps[i * 256 + tid];
        float4 c = pq[i * 256 + tid];
        s += (a.x + a.y) + (a.z + a.w);
        q += (c.x + c.y) + (c.z + c.w);
    }

    __shared__ float sS[4], sQ[4];
#pragma unroll
    for (int off = 32; off > 0; off >>= 1) {
        s += __shfl_down(s, off, 64);
        q += __shfl_down(q, off, 64);
    }
    const int lane = tid & 63, wid = tid >> 6;
    if (lane == 0) { sS[wid] = s; sQ[wid] = q; }
    __syncthreads();
    if (tid == 0) {
        float sum = (sS[0] + sS[1]) + (sS[2] + sS[3]);
        float sq  = (sQ[0] + sQ[1]) + (sQ[2] + sQ[3]);
        const float invN = 1.0f / (float)(BATCH * NFACES);
        float mean = sum * invN;
        float var  = sq * invN - mean * mean;
        float sc = gamma[k] / sqrtf(var + 1e-5f);
        scale[k] = sc;
        shift[k] = beta[k] - mean * sc;
    }
}

__global__ __launch_bounds__(256) void bn_kernel(
    float* __restrict__ out,
    const float* __restrict__ scale,
    const float* __restrict__ shift)
{
    const size_t idx = (size_t)blockIdx.x * 256 + threadIdx.x;  // float4 index
    const int k = (int)((idx >> 12) & 63);   // 4096 f4 per (b,k) row
    float4 v = reinterpret_cast<float4*>(out)[idx];
    const float sc = scale[k], sh = shift[k];
    v.x = fmaxf(__builtin_fmaf(v.x, sc, sh), 0.0f);
    v.y = fmaxf(__builtin_fmaf(v.y, sc, sh), 0.0f);
    v.z = fmaxf(__builtin_fmaf(v.z, sc, sh), 0.0f);
    v.w = fmaxf(__builtin_fmaf(v.w, sc, sh), 0.0f);
    reinterpret_cast<float4*>(out)[idx] = v;
}

extern "C" void kernel_launch(void* const* d_in, const int* in_sizes, int n_in,
                              void* d_out, int out_size, void* d_ws, size_t ws_size,
                              hipStream_t stream) {
    const float* normals = (const float*)d_in[0];
    const int*   nbr     = (const int*)d_in[1];
    const float* walpha  = (const float*)d_in[2];
    const float* wbeta   = (const float*)d_in[3];
    const float* gamma   = (const float*)d_in[4];
    const float* beta    = (const float*)d_in[5];
    float* out = (float*)d_out;

    float* psum   = (float*)d_ws;              // [64][2048]
    float* psumsq = psum + KK * NBLK;          // [64][2048]
    float* scale  = psumsq + KK * NBLK;        // [64]
    float* shift  = scale + KK;                // [64]

    kc_kernel<<<NBLK, 256, 0, stream>>>(normals, nbr, walpha, wbeta, out, psum, psumsq);
    fin_kernel<<<KK, 256, 0, stream>>>(psum, psumsq, gamma, beta, scale, shift);

    const int total_f4 = (BATCH * KK * NFACES) / 4;   // 2,097,152
    bn_kernel<<<total_f4 / 256, 256, 0, stream>>>(out, scale, shift);
}

// Round 8
// 53.308 us; speedup vs baseline: 1.5439x; 1.0142x over previous
//
#include <hip/hip_runtime.h>
#include <math.h>

// FaceKernelCorrelation: B=8, N=16384, K=64, 4 kernel points per k, sigma=0.2
// R8: attack kc's inner loop (R7: 40.4us, VALUBusy 64%, VGPR 36 -> compiler
// under-unrolled, no w-prefetch, 16-deep serial acc chain). Changes:
//   - full kk unroll + explicit next-kk register prefetch of the 4 w's
//   - 4 independent per-j accumulators (acc chain 16 -> 4 + tree)
//   - __launch_bounds__(256,4): VGPR cap 128 (LDS still limits to 7 blk/CU)
//  1) kc_kernel:  gather fea, compute kc[b,k,n], store, fused stats partials.
//  2) fin_kernel: 64 blocks (one per k): reduce 2048 partials -> scale/shift.
//  3) bn_kernel:  in-place float4 y = relu(kc*scale + shift).

#define NFACES 16384
#define BATCH  8
#define KK     64
#define NBLK   2048            // kc grid: BATCH * (NFACES/64)

// C = -1/(2*sigma^2) * log2(e)  with sigma = 0.2
__device__ __constant__ const float C_SCALE = -18.033688011112043f;

__global__ __launch_bounds__(256, 4) void kc_kernel(
    const float* __restrict__ normals,   // [B,3,N]
    const int*   __restrict__ nbr,       // [B,N,3]
    const float* __restrict__ walpha,    // [K*4]
    const float* __restrict__ wbeta,     // [K*4]
    float*       __restrict__ out,       // [B,K,N] (kc values)
    float*       __restrict__ psum,      // [K][NBLK]
    float*       __restrict__ psumsq)    // [K][NBLK]
{
    __shared__ float4 sW[KK * 4];        // (m2*wx, m2*wy, m2*wz, C*|w|^2)
    __shared__ float  sT[4][64][17];     // [wave][lane][k] transpose tile

    const int tid = threadIdx.x;

    // Build kernel-point table: 256 threads -> 256 (k,j) entries
    {
        float a = walpha[tid];
        float b = wbeta[tid];
        float sa = sinf(a), ca = cosf(a);
        float sb = sinf(b), cb = cosf(b);
        float wx = sa * cb, wy = sa * sb, wz = ca;
        float wn2 = wx * wx + wy * wy + wz * wz;
        const float m2 = -2.0f * C_SCALE;
        sW[tid] = make_float4(m2 * wx, m2 * wy, m2 * wz, C_SCALE * wn2);
    }
    __syncthreads();

    const int b    = blockIdx.x >> 8;                       // blockIdx / 256
    const int lane = tid & 63;
    const int n    = ((blockIdx.x & 255) << 6) + lane;      // face index
    const int kq   = tid >> 6;                              // wave id: k-quarter

    const float* nb_ = normals + (size_t)b * 3 * NFACES;

    float fx[4], fy[4], fz[4], fa[4];
    fx[0] = nb_[n];
    fy[0] = nb_[NFACES + n];
    fz[0] = nb_[2 * NFACES + n];
    const int* ip = nbr + ((size_t)b * NFACES + n) * 3;
#pragma unroll
    for (int j = 0; j < 3; ++j) {
        int idx = ip[j];
        fx[j + 1] = nb_[idx];
        fy[j + 1] = nb_[NFACES + idx];
        fz[j + 1] = nb_[2 * NFACES + idx];
    }
#pragma unroll
    for (int i = 0; i < 4; ++i)
        fa[i] = C_SCALE * (fx[i] * fx[i] + fy[i] * fy[i] + fz[i] * fz[i]);

    float* outp = out + ((size_t)b * KK + kq * 16) * NFACES + n;
    const float4* wp = &sW[kq * 64];

    // Preload first kk's 4 kernel points into registers.
    float4 wa = wp[0], wb = wp[1], wc = wp[2], wd = wp[3];

#pragma unroll
    for (int kk = 0; kk < 16; ++kk) {
        // Prefetch next kk's w's while computing this one.
        float4 na, nb2, nc, nd;
        if (kk < 15) {
            na  = wp[kk * 4 + 4];
            nb2 = wp[kk * 4 + 5];
            nc  = wp[kk * 4 + 6];
            nd  = wp[kk * 4 + 7];
        }

        float s0 = 0.0f, s1 = 0.0f, s2 = 0.0f, s3 = 0.0f;
#pragma unroll
        for (int i = 0; i < 4; ++i) {
            float t0 = __builtin_fmaf(wa.x, fx[i],
                        __builtin_fmaf(wa.y, fy[i],
                         __builtin_fmaf(wa.z, fz[i], wa.w))) + fa[i];
            float t1 = __builtin_fmaf(wb.x, fx[i],
                        __builtin_fmaf(wb.y, fy[i],
                         __builtin_fmaf(wb.z, fz[i], wb.w))) + fa[i];
            float t2 = __builtin_fmaf(wc.x, fx[i],
                        __builtin_fmaf(wc.y, fy[i],
                         __builtin_fmaf(wc.z, fz[i], wc.w))) + fa[i];
            float t3 = __builtin_fmaf(wd.x, fx[i],
                        __builtin_fmaf(wd.y, fy[i],
                         __builtin_fmaf(wd.z, fz[i], wd.w))) + fa[i];
            s0 += __builtin_amdgcn_exp2f(t0);
            s1 += __builtin_amdgcn_exp2f(t1);
            s2 += __builtin_amdgcn_exp2f(t2);
            s3 += __builtin_amdgcn_exp2f(t3);
        }
        float kc = ((s0 + s1) + (s2 + s3)) * 0.0625f;
        outp[(size_t)kk * NFACES] = kc;
        sT[kq][lane][kk] = kc;               // intra-wave: no barrier needed

        wa = na; wb = nb2; wc = nc; wd = nd;
    }

    // Per-wave transpose reduce over this wave's 64 faces, 16 k's.
    // Reads: bank = (16*seg + 17*j + kk) % 32 -> exactly 2-way, free.
    {
        const int kk = lane & 15, seg = lane >> 4;
        float v = 0.0f, q = 0.0f;
#pragma unroll
        for (int j = 0; j < 16; ++j) {
            float x = sT[kq][seg * 16 + j][kk];
            v += x;
            q = __builtin_fmaf(x, x, q);
        }
        v += __shfl_xor(v, 16, 64);  q += __shfl_xor(q, 16, 64);
        v += __shfl_xor(v, 32, 64);  q += __shfl_xor(q, 32, 64);
        if (seg == 0) {
            const int k = kq * 16 + kk;
            psum[(size_t)k * NBLK + blockIdx.x]   = v;
            psumsq[(size_t)k * NBLK + blockIdx.x] = q;
        }
    }
}

// One block per k: reduce 2048 partials -> scale/shift.
__global__ __launch_bounds__(256) void fin_kernel(
    const float* __restrict__ psum,
    const float* __restrict__ psumsq,
    const float* __restrict__ gamma,
    const float* __restrict__ beta,
    float*       __restrict__ scale,
    float*       __restrict__ shift)
{
    const int k = blockIdx.x;
    const int tid = threadIdx.x;
    const float4* ps = reinterpret_cast<const float4*>(psum   + (size_t)k * NBLK);
    const float4* pq = reinterpret_cast<const float4*>(psumsq + (size_t)k * NBLK);

    float s = 0.0f, q = 0.0f;
#pragma unroll
    for (int i = 0; i < 2; ++i) {
        float4 a = ps[i * 256 + tid];
        float4 c = pq[i * 256 + tid];
        s += (a.x + a.y) + (a.z + a.w);
        q += (c.x + c.y) + (c.z + c.w);
    }

    __shared__ float sS[4], sQ[4];
#pragma unroll
    for (int off = 32; off > 0; off >>= 1) {
        s += __shfl_down(s, off, 64);
        q += __shfl_down(q, off, 64);
    }
    const int lane = tid & 63, wid = tid >> 6;
    if (lane == 0) { sS[wid] = s; sQ[wid] = q; }
    __syncthreads();
    if (tid == 0) {
        float sum = (sS[0] + sS[1]) + (sS[2] + sS[3]);
        float sq  = (sQ[0] + sQ[1]) + (sQ[2] + sQ[3]);
        const float invN = 1.0f / (float)(BATCH * NFACES);
        float mean = sum * invN;
        float var  = sq * invN - mean * mean;
        float sc = gamma[k] / sqrtf(var + 1e-5f);
        scale[k] = sc;
        shift[k] = beta[k] - mean * sc;
    }
}

__global__ __launch_bounds__(256) void bn_kernel(
    float* __restrict__ out,
    const float* __restrict__ scale,
    const float* __restrict__ shift)
{
    const size_t idx = (size_t)blockIdx.x * 256 + threadIdx.x;  // float4 index
    const int k = (int)((idx >> 12) & 63);   // 4096 f4 per (b,k) row
    float4 v = reinterpret_cast<float4*>(out)[idx];
    const float sc = scale[k], sh = shift[k];
    v.x = fmaxf(__builtin_fmaf(v.x, sc, sh), 0.0f);
    v.y = fmaxf(__builtin_fmaf(v.y, sc, sh), 0.0f);
    v.z = fmaxf(__builtin_fmaf(v.z, sc, sh), 0.0f);
    v.w = fmaxf(__builtin_fmaf(v.w, sc, sh), 0.0f);
    reinterpret_cast<float4*>(out)[idx] = v;
}

extern "C" void kernel_launch(void* const* d_in, const int* in_sizes, int n_in,
                              void* d_out, int out_size, void* d_ws, size_t ws_size,
                              hipStream_t stream) {
    const float* normals = (const float*)d_in[0];
    const int*   nbr     = (const int*)d_in[1];
    const float* walpha  = (const float*)d_in[2];
    const float* wbeta   = (const float*)d_in[3];
    const float* gamma   = (const float*)d_in[4];
    const float* beta    = (const float*)d_in[5];
    float* out = (float*)d_out;

    float* psum   = (float*)d_ws;              // [64][2048]
    float* psumsq = psum + KK * NBLK;          // [64][2048]
    float* scale  = psumsq + KK * NBLK;        // [64]
    float* shift  = scale + KK;                // [64]

    kc_kernel<<<NBLK, 256, 0, stream>>>(normals, nbr, walpha, wbeta, out, psum, psumsq);
    fin_kernel<<<KK, 256, 0, stream>>>(psum, psumsq, gamma, beta, scale, shift);

    const int total_f4 = (BATCH * KK * NFACES) / 4;   // 2,097,152
    bn_kernel<<<total_f4 / 256, 256, 0, stream>>>(out, scale, shift);
}